// Round 3
// baseline (765.337 us; speedup 1.0000x reference)
//
#include <hip/hip_runtime.h>
#include <cmath>

// node_learning: out = tanh((adj @ X) @ Wn^T + X @ Ws^T)
// Fold: (adj@X)@Wn^T == adj@(X@Wn^T).  Big GEMM in bf16 hi/lo split
// (3 MFMA passes: hh + hl + lh, rel err ~2^-17) -> memory-bound,
// adj-read floor ~63us.
// R3: barrier-free GEMM. No LDS at all: MFMA fragments loaded straight
// from global into registers in fragment layout (A rows from adj, fp32 ->
// bf16 hi/lo in-register; B from pre-split transposed xnt). A-row overlap
// between the 2 m-waves of a block is absorbed by L1. One-subtile register
// rotation (load k+32 while MFMA'ing k) -> compiler pipelines with
// fine-grained vmcnt, no s_barrier drain. NKCH 13->7 halves P traffic.

#define N_NODES 10000
#define EMB 128
#define XNT_STRIDE 10240   // padded row length (elems) of transposed Xn
#define KC 1440            // K-chunk per block in main GEMM (45 subtiles of 32)
#define NKCH 7             // ceil(10000/1440)

typedef __bf16 bf16x8 __attribute__((ext_vector_type(8)));
typedef float  f32x4  __attribute__((ext_vector_type(4)));

__device__ __forceinline__ bf16x8 bzero8() {
    bf16x8 v;
#pragma unroll
    for (int i = 0; i < 8; ++i) v[i] = (__bf16)0.0f;
    return v;
}

// split 8 fp32 into bf16 hi + bf16 lo(residual)
__device__ __forceinline__ void split8(const float4& x0, const float4& x1,
                                       bf16x8& h, bf16x8& l) {
    float f[8] = {x0.x, x0.y, x0.z, x0.w, x1.x, x1.y, x1.z, x1.w};
#pragma unroll
    for (int i = 0; i < 8; ++i) {
        __bf16 hh = (__bf16)f[i];
        h[i] = hh;
        l[i] = (__bf16)(f[i] - (float)hh);
    }
}

// ---------------------------------------------------------------------------
// prep: Xn = X @ Wn^T  (fp32), split to bf16 hi/lo, store transposed
// xnt[c][n], row stride XNT_STRIDE.  Vector 16B stores (10000 % 16 == 0).
// ---------------------------------------------------------------------------
__global__ __launch_bounds__(256) void prep_kernel(
    const float* __restrict__ X, const float* __restrict__ Wn,
    __bf16* __restrict__ xnt_hi, __bf16* __restrict__ xnt_lo)
{
    __shared__ float Xl[32 * EMB];
    const int tid = threadIdx.x;
    const int n0 = blockIdx.x * 32;

#pragma unroll
    for (int i = 0; i < 4; ++i) {
        int idx = tid + i * 256;            // float4 index 0..1023
        int r = idx >> 5;
        int c4 = (idx & 31) << 2;
        int row = n0 + r;
        float4 v = make_float4(0.f, 0.f, 0.f, 0.f);
        if (row < N_NODES) v = *(const float4*)(X + (size_t)row * EMB + c4);
        *(float4*)(Xl + r * EMB + c4) = v;
    }
    __syncthreads();

    const int c = tid & 127;
    const int half = tid >> 7;
    const float* wrow = Wn + c * EMB;

    float acc[16];
#pragma unroll
    for (int r = 0; r < 16; ++r) acc[r] = 0.f;

    for (int k4 = 0; k4 < 32; ++k4) {
        float4 w = *(const float4*)(wrow + k4 * 4);
#pragma unroll
        for (int r = 0; r < 16; ++r) {
            float4 x = *(const float4*)(Xl + (half * 16 + r) * EMB + k4 * 4);
            acc[r] += x.x * w.x + x.y * w.y + x.z * w.z + x.w * w.w;
        }
    }

    // rows n0+half*16 .. +15 all valid or all invalid (10000 % 16 == 0)
    if (n0 + half * 16 < N_NODES) {
        bf16x8 h0, h1, l0, l1;
#pragma unroll
        for (int r = 0; r < 16; ++r) {
            float f = acc[r];
            __bf16 h = (__bf16)f;
            __bf16 l = (__bf16)(f - (float)h);
            if (r < 8) { h0[r] = h; l0[r] = l; }
            else       { h1[r - 8] = h; l1[r - 8] = l; }
        }
        size_t base = (size_t)c * XNT_STRIDE + n0 + half * 16;
        *(bf16x8*)(xnt_hi + base)     = h0;
        *(bf16x8*)(xnt_hi + base + 8) = h1;
        *(bf16x8*)(xnt_lo + base)     = l0;
        *(bf16x8*)(xnt_lo + base + 8) = l1;
    }
}

// ---------------------------------------------------------------------------
// gemm (barrier-free, LDS-free):
// P[kc] = adj[m0:m0+128, kc range] @ Xn[kc range, :]
// Fragments loaded straight from global in MFMA layout:
//   A frag (tile mt): lane -> adj[m0+wm+mt*16+fr][k0+q*8 .. +8]  (fp32->hi/lo)
//   B frag (tile nt): lane -> xnt[wn+nt*16+fr][k0+q*8 .. +8]     (pre-split)
// ---------------------------------------------------------------------------
struct SubTile {
    float4 a0[4], a1[4];    // raw fp32 A, 8 per tile
    bf16x8 bh[4], bl[4];    // pre-split B
};

__device__ __forceinline__ void load_sub(
    const float* const (&arow)[4], const bool (&arv)[4],
    const __bf16* const (&bhp)[4], const __bf16* const (&blp)[4],
    int k, int kc_end, SubTile& s)
{
    const bool kv = k < kc_end;     // k is 8-aligned, kc_end % 8 == 0
#pragma unroll
    for (int t = 0; t < 4; ++t) {
        float4 v0 = make_float4(0.f, 0.f, 0.f, 0.f);
        float4 v1 = v0;
        if (kv && arv[t]) {
            v0 = *(const float4*)(arow[t] + k);
            v1 = *(const float4*)(arow[t] + k + 4);
        }
        s.a0[t] = v0;
        s.a1[t] = v1;
        bf16x8 h = bzero8(), l = bzero8();
        if (kv) {
            h = *(const bf16x8*)(bhp[t] + k);
            l = *(const bf16x8*)(blp[t] + k);
        }
        s.bh[t] = h;
        s.bl[t] = l;
    }
}

__global__ __launch_bounds__(256, 2) void gemm_kernel(
    const float* __restrict__ adj, const __bf16* __restrict__ xnt_hi,
    const __bf16* __restrict__ xnt_lo, float* __restrict__ Ppart)
{
    const int tid = threadIdx.x;
    const int m0 = blockIdx.x * 128;
    const int kc0 = blockIdx.y * KC;
    const int kc_end = min(kc0 + KC, N_NODES);
    const int nsub = (kc_end - kc0 + 31) >> 5;

    const int lane = tid & 63;
    const int wave = tid >> 6;
    const int wm = (wave & 1) * 64;
    const int wn = (wave >> 1) * 64;
    const int fr = lane & 15;   // row (A) / col (B) within 16-tile
    const int q  = lane >> 4;   // k-quad: k offset q*8
    const int q8 = q * 8;

    const float* arow[4];
    bool arv[4];
    const __bf16* bhp[4];
    const __bf16* blp[4];
#pragma unroll
    for (int t = 0; t < 4; ++t) {
        int row = m0 + wm + t * 16 + fr;
        arv[t] = row < N_NODES;
        arow[t] = adj + (size_t)(arv[t] ? row : 0) * N_NODES;
        int col = wn + t * 16 + fr;          // < 128 always
        bhp[t] = xnt_hi + (size_t)col * XNT_STRIDE;
        blp[t] = xnt_lo + (size_t)col * XNT_STRIDE;
    }

    f32x4 acc[4][4];
#pragma unroll
    for (int mt = 0; mt < 4; ++mt)
#pragma unroll
        for (int nt = 0; nt < 4; ++nt)
#pragma unroll
            for (int e = 0; e < 4; ++e) acc[mt][nt][e] = 0.f;

    SubTile cur, nxt;
    load_sub(arow, arv, bhp, blp, kc0 + q8, kc_end, cur);

    for (int ks = 0; ks < nsub; ++ks) {
        // issue next subtile's loads (guards make past-end lanes zero)
        load_sub(arow, arv, bhp, blp, kc0 + (ks + 1) * 32 + q8, kc_end, nxt);

        // convert current A to hi/lo fragments
        bf16x8 ah[4], al[4];
#pragma unroll
        for (int t = 0; t < 4; ++t) split8(cur.a0[t], cur.a1[t], ah[t], al[t]);

#pragma unroll
        for (int mt = 0; mt < 4; ++mt)
#pragma unroll
            for (int nt = 0; nt < 4; ++nt) {
                acc[mt][nt] = __builtin_amdgcn_mfma_f32_16x16x32_bf16(ah[mt], cur.bh[nt], acc[mt][nt], 0, 0, 0);
                acc[mt][nt] = __builtin_amdgcn_mfma_f32_16x16x32_bf16(ah[mt], cur.bl[nt], acc[mt][nt], 0, 0, 0);
                acc[mt][nt] = __builtin_amdgcn_mfma_f32_16x16x32_bf16(al[mt], cur.bh[nt], acc[mt][nt], 0, 0, 0);
            }
        cur = nxt;
    }

    // C/D layout (verified m89): col = lane&15, row = (lane>>4)*4 + reg
    float* P = Ppart + (size_t)blockIdx.y * ((size_t)N_NODES * EMB);
#pragma unroll
    for (int mt = 0; mt < 4; ++mt) {
        int rbase = m0 + wm + mt * 16 + q * 4;
#pragma unroll
        for (int nt = 0; nt < 4; ++nt) {
            int col = wn + nt * 16 + fr;
#pragma unroll
            for (int r = 0; r < 4; ++r) {
                int row = rbase + r;
                if (row < N_NODES)
                    P[(size_t)row * EMB + col] = acc[mt][nt][r];
            }
        }
    }
}

// ---------------------------------------------------------------------------
// epi (fast path): out = tanh(sum_p P[p] + X @ Ws^T)
// ---------------------------------------------------------------------------
__global__ __launch_bounds__(256) void epi_kernel(
    const float* __restrict__ X, const float* __restrict__ Wself,
    const float* __restrict__ Ppart, float* __restrict__ out)
{
    __shared__ float Xl[32 * EMB];
    const int tid = threadIdx.x;
    const int n0 = blockIdx.x * 32;

#pragma unroll
    for (int i = 0; i < 4; ++i) {
        int idx = tid + i * 256;
        int r = idx >> 5;
        int c4 = (idx & 31) << 2;
        int row = n0 + r;
        float4 v = make_float4(0.f, 0.f, 0.f, 0.f);
        if (row < N_NODES) v = *(const float4*)(X + (size_t)row * EMB + c4);
        *(float4*)(Xl + r * EMB + c4) = v;
    }
    __syncthreads();

    const int c = tid & 127;
    const int half = tid >> 7;
    const float* wrow = Wself + c * EMB;

    float acc[16];
#pragma unroll
    for (int r = 0; r < 16; ++r) acc[r] = 0.f;

    for (int k4 = 0; k4 < 32; ++k4) {
        float4 w = *(const float4*)(wrow + k4 * 4);
#pragma unroll
        for (int r = 0; r < 16; ++r) {
            float4 x = *(const float4*)(Xl + (half * 16 + r) * EMB + k4 * 4);
            acc[r] += x.x * w.x + x.y * w.y + x.z * w.z + x.w * w.w;
        }
    }

    if (n0 + half * 16 < N_NODES) {   // whole 16-row group valid (10000%16==0)
        const size_t rb = (size_t)(n0 + half * 16) * EMB + c;
        // reduce the K-chunk partials (coalesced: lanes span c)
#pragma unroll
        for (int p = 0; p < NKCH; ++p) {
            const float* Pp = Ppart + (size_t)p * ((size_t)N_NODES * EMB) + rb;
#pragma unroll
            for (int r = 0; r < 16; ++r)
                acc[r] += Pp[(size_t)r * EMB];
        }
#pragma unroll
        for (int r = 0; r < 16; ++r)
            out[rb + (size_t)r * EMB] = tanhf(acc[r]);
    }
}

// ---------------------------------------------------------------------------
// Fallback path (ws too small): fp32 VALU GEMM Y = adj@X atomically into out,
// then epi0 applies both weight matrices + tanh.
// ---------------------------------------------------------------------------
__global__ __launch_bounds__(256) void gemm0_kernel(
    const float* __restrict__ adj, const float* __restrict__ X,
    float* __restrict__ Y)
{
    __shared__ float As[128 * 33];
    __shared__ float Xs[32 * 132];
    const int tid = threadIdx.x;
    const int m0 = blockIdx.x * 128;
    const int kc0 = blockIdx.y * KC;
    const int kc_end = min(kc0 + KC, N_NODES);
    const int nsub = (kc_end - kc0 + 31) >> 5;

    const int am = tid >> 1, akq = tid & 1;
    const bool arv = (m0 + am) < N_NODES;
    const float* arow_p = adj + (size_t)(m0 + am) * N_NODES;
    const int xr = tid >> 3, xq = tid & 7;
    const int mq = tid >> 4, nq = tid & 15;

    float acc[8][8];
#pragma unroll
    for (int i = 0; i < 8; ++i)
#pragma unroll
        for (int j = 0; j < 8; ++j) acc[i][j] = 0.f;

    for (int ks = 0; ks < nsub; ++ks) {
        int k0 = kc0 + ks * 32;
#pragma unroll
        for (int i = 0; i < 4; ++i) {
            int k = k0 + akq * 16 + i * 4;
            float4 v = make_float4(0.f, 0.f, 0.f, 0.f);
            if (arv && k < kc_end) v = *(const float4*)(arow_p + k);
            float* d = As + am * 33 + akq * 16 + i * 4;
            d[0] = v.x; d[1] = v.y; d[2] = v.z; d[3] = v.w;
        }
#pragma unroll
        for (int i = 0; i < 4; ++i) {
            int c0 = xq * 16 + i * 4;
            int krow = k0 + xr;
            float4 v = make_float4(0.f, 0.f, 0.f, 0.f);
            if (krow < kc_end) v = *(const float4*)(X + (size_t)krow * EMB + c0);
            *(float4*)(Xs + xr * 132 + c0) = v;
        }
        __syncthreads();
        for (int k = 0; k < 32; ++k) {
            float a8[8];
#pragma unroll
            for (int i = 0; i < 8; ++i) a8[i] = As[(mq * 8 + i) * 33 + k];
            float4 x0 = *(const float4*)(Xs + k * 132 + nq * 8);
            float4 x1 = *(const float4*)(Xs + k * 132 + nq * 8 + 4);
            float x8[8] = { x0.x, x0.y, x0.z, x0.w, x1.x, x1.y, x1.z, x1.w };
#pragma unroll
            for (int i = 0; i < 8; ++i)
#pragma unroll
                for (int j = 0; j < 8; ++j) acc[i][j] += a8[i] * x8[j];
        }
        __syncthreads();
    }
#pragma unroll
    for (int i = 0; i < 8; ++i) {
        int row = m0 + mq * 8 + i;
        if (row < N_NODES) {
#pragma unroll
            for (int j = 0; j < 8; ++j)
                atomicAdd(Y + (size_t)row * EMB + nq * 8 + j, acc[i][j]);
        }
    }
}

__global__ __launch_bounds__(256) void epi0_kernel(
    const float* __restrict__ X, const float* __restrict__ Wn,
    const float* __restrict__ Ws, float* __restrict__ out)
{
    __shared__ float Xl[32 * EMB];
    __shared__ float Yl[32 * EMB];
    const int tid = threadIdx.x;
    const int n0 = blockIdx.x * 32;

#pragma unroll
    for (int i = 0; i < 4; ++i) {
        int idx = tid + i * 256;
        int r = idx >> 5;
        int c4 = (idx & 31) << 2;
        int row = n0 + r;
        float4 vx = make_float4(0.f, 0.f, 0.f, 0.f);
        float4 vy = vx;
        if (row < N_NODES) {
            vx = *(const float4*)(X + (size_t)row * EMB + c4);
            vy = *(const float4*)(out + (size_t)row * EMB + c4);
        }
        *(float4*)(Xl + r * EMB + c4) = vx;
        *(float4*)(Yl + r * EMB + c4) = vy;
    }
    __syncthreads();

    const int c = tid & 127;
    const int half = tid >> 7;
    const float* wn = Wn + c * EMB;
    const float* ws = Ws + c * EMB;

    float accn[16], accs[16];
#pragma unroll
    for (int r = 0; r < 16; ++r) { accn[r] = 0.f; accs[r] = 0.f; }

    for (int k4 = 0; k4 < 32; ++k4) {
        float4 a = *(const float4*)(wn + k4 * 4);
        float4 b = *(const float4*)(ws + k4 * 4);
#pragma unroll
        for (int r = 0; r < 16; ++r) {
            float4 y = *(const float4*)(Yl + (half * 16 + r) * EMB + k4 * 4);
            float4 x = *(const float4*)(Xl + (half * 16 + r) * EMB + k4 * 4);
            accn[r] += y.x * a.x + y.y * a.y + y.z * a.z + y.w * a.w;
            accs[r] += x.x * b.x + x.y * b.y + x.z * b.z + x.w * b.w;
        }
    }
#pragma unroll
    for (int r = 0; r < 16; ++r) {
        int row = n0 + half * 16 + r;
        if (row < N_NODES)
            out[(size_t)row * EMB + c] = tanhf(accn[r] + accs[r]);
    }
}

// ---------------------------------------------------------------------------
extern "C" void kernel_launch(void* const* d_in, const int* in_sizes, int n_in,
                              void* d_out, int out_size, void* d_ws, size_t ws_size,
                              hipStream_t stream) {
    const float* adj = (const float*)d_in[0];
    const float* X   = (const float*)d_in[1];
    const float* Wn  = (const float*)d_in[2];
    const float* Ws  = (const float*)d_in[3];
    float* out = (float*)d_out;

    const size_t xnt_elems = (size_t)EMB * XNT_STRIDE;
    const size_t xnt_bytes = xnt_elems * 2 * sizeof(unsigned short);   // hi+lo
    const size_t part_bytes = (size_t)NKCH * N_NODES * EMB * sizeof(float);

    if (ws_size >= xnt_bytes + part_bytes) {
        // fast path: partials in ws, no atomics, no d_out memset
        __bf16* xh = (__bf16*)d_ws;
        __bf16* xl = xh + xnt_elems;
        float* Ppart = (float*)((char*)d_ws + xnt_bytes);
        prep_kernel<<<(N_NODES + 31) / 32, 256, 0, stream>>>(X, Wn, xh, xl);
        gemm_kernel<<<dim3((N_NODES + 127) / 128, NKCH), 256, 0, stream>>>(adj, xh, xl, Ppart);
        epi_kernel<<<(N_NODES + 31) / 32, 256, 0, stream>>>(X, Ws, Ppart, out);
    } else {
        // fallback: fp32 VALU GEMM with atomics into pre-zeroed out
        hipMemsetAsync(d_out, 0, (size_t)N_NODES * EMB * sizeof(float), stream);
        gemm0_kernel<<<dim3((N_NODES + 127) / 128, NKCH), 256, 0, stream>>>(adj, X, out);
        epi0_kernel<<<(N_NODES + 31) / 32, 256, 0, stream>>>(X, Wn, Ws, out);
    }
}

// Round 4
// 606.447 us; speedup vs baseline: 1.2620x; 1.2620x over previous
//
#include <hip/hip_runtime.h>
#include <cmath>

// node_learning: out = tanh((adj @ X) @ Wn^T + X @ Ws^T)
// Fold: (adj@X)@Wn^T == adj@(X@Wn^T).  Big GEMM in bf16 hi/lo split
// (3 MFMA passes: hh + hl + lh, rel err ~2^-17) -> memory-bound,
// adj-read floor ~45-63us (harness's adj-restore warms L3).
// R4: m97-style K-loop. global_load_lds(16B) stages A (raw fp32) and B
// (pre-split bf16 hi/lo) straight into LDS; A converted to bf16 hi/lo after
// ds_read. BK=64 (13 barrier-pairs/block), 64KB LDS -> 2 blocks/CU so one
// block's barrier drain hides under the other's MFMA. XOR quad-swizzle on
// the *source* address (global_load_lds dest is lane-fixed) makes fragment
// ds_reads 2-way/bank = free. xnt k-pad [10000,10240) zeroed so last-chunk
// overreach multiplies clamped-A garbage by exact zeros.

#define N_NODES 10000
#define EMB 128
#define XNT_STRIDE 10240   // padded row length (elems) of transposed Xn
#define KC 832             // K-chunk per block: 13 BK=64 iters
#define NKCH 13            // ceil(10000/832)

typedef __bf16 bf16x8 __attribute__((ext_vector_type(8)));
typedef float  f32x4  __attribute__((ext_vector_type(4)));

#define GLOAD_LDS16(gp, lp)                                                  \
    __builtin_amdgcn_global_load_lds(                                        \
        (const __attribute__((address_space(1))) void*)(gp),                 \
        (__attribute__((address_space(3))) void*)(lp), 16, 0, 0)

// split 8 fp32 into bf16 hi + bf16 lo(residual)
__device__ __forceinline__ void split8(const float4& x0, const float4& x1,
                                       bf16x8& h, bf16x8& l) {
    float f[8] = {x0.x, x0.y, x0.z, x0.w, x1.x, x1.y, x1.z, x1.w};
#pragma unroll
    for (int i = 0; i < 8; ++i) {
        __bf16 hh = (__bf16)f[i];
        h[i] = hh;
        l[i] = (__bf16)(f[i] - (float)hh);
    }
}

// ---------------------------------------------------------------------------
// prep: Xn = X @ Wn^T  (fp32), split to bf16 hi/lo, store transposed
// xnt[c][n], row stride XNT_STRIDE.  Block 0 also zeroes the k-pad region
// [10000, 10240) of every column (read by gemm's last K-chunk).
// ---------------------------------------------------------------------------
__global__ __launch_bounds__(256) void prep_kernel(
    const float* __restrict__ X, const float* __restrict__ Wn,
    __bf16* __restrict__ xnt_hi, __bf16* __restrict__ xnt_lo)
{
    __shared__ float Xl[32 * EMB];
    const int tid = threadIdx.x;
    const int n0 = blockIdx.x * 32;

    if (blockIdx.x == 0) {
        // zero pad region: 128 cols x 240 elems = 3840 groups of 8
        bf16x8 z;
#pragma unroll
        for (int i = 0; i < 8; ++i) z[i] = (__bf16)0.0f;
        for (int g = tid; g < 128 * 30; g += 256) {
            int col = g / 30, j = g % 30;
            size_t off = (size_t)col * XNT_STRIDE + N_NODES + j * 8;
            *(bf16x8*)(xnt_hi + off) = z;
            *(bf16x8*)(xnt_lo + off) = z;
        }
    }

#pragma unroll
    for (int i = 0; i < 4; ++i) {
        int idx = tid + i * 256;            // float4 index 0..1023
        int r = idx >> 5;
        int c4 = (idx & 31) << 2;
        int row = n0 + r;
        float4 v = make_float4(0.f, 0.f, 0.f, 0.f);
        if (row < N_NODES) v = *(const float4*)(X + (size_t)row * EMB + c4);
        *(float4*)(Xl + r * EMB + c4) = v;
    }
    __syncthreads();

    const int c = tid & 127;
    const int half = tid >> 7;
    const float* wrow = Wn + c * EMB;

    float acc[16];
#pragma unroll
    for (int r = 0; r < 16; ++r) acc[r] = 0.f;

    for (int k4 = 0; k4 < 32; ++k4) {
        float4 w = *(const float4*)(wrow + k4 * 4);
#pragma unroll
        for (int r = 0; r < 16; ++r) {
            float4 x = *(const float4*)(Xl + (half * 16 + r) * EMB + k4 * 4);
            acc[r] += x.x * w.x + x.y * w.y + x.z * w.z + x.w * w.w;
        }
    }

    // rows n0+half*16 .. +15 all valid or all invalid (10000 % 16 == 0)
    if (n0 + half * 16 < N_NODES) {
        bf16x8 h0, h1, l0, l1;
#pragma unroll
        for (int r = 0; r < 16; ++r) {
            float f = acc[r];
            __bf16 h = (__bf16)f;
            __bf16 l = (__bf16)(f - (float)h);
            if (r < 8) { h0[r] = h; l0[r] = l; }
            else       { h1[r - 8] = h; l1[r - 8] = l; }
        }
        size_t base = (size_t)c * XNT_STRIDE + n0 + half * 16;
        *(bf16x8*)(xnt_hi + base)     = h0;
        *(bf16x8*)(xnt_hi + base + 8) = h1;
        *(bf16x8*)(xnt_lo + base)     = l0;
        *(bf16x8*)(xnt_lo + base + 8) = l1;
    }
}

// ---------------------------------------------------------------------------
// gemm: P[kc] = adj[m0:m0+128, kc range] @ Xn[kc range, :]
// BK=64 per barrier-pair; global_load_lds staging; swizzled LDS layouts:
//   Af  : fp32 [row][quad pc], pc = c ^ (row&7), row stride 64 fp32
//   Bh/l: bf16 [col][quad pq], pq = kq ^ (col&7), col stride 64 bf16
// ---------------------------------------------------------------------------
__global__ __launch_bounds__(256, 2) void gemm_kernel(
    const float* __restrict__ adj, const __bf16* __restrict__ xnt_hi,
    const __bf16* __restrict__ xnt_lo, float* __restrict__ Ppart)
{
    __shared__ float  Af [128 * 64];   // 32 KB
    __shared__ __bf16 Bhs[128 * 64];   // 16 KB
    __shared__ __bf16 Bls[128 * 64];   // 16 KB

    const int tid = threadIdx.x;
    const int m0 = blockIdx.x * 128;
    const int kc0 = blockIdx.y * KC;
    const int kc_end = min(kc0 + KC, N_NODES);
    const int nsub = (kc_end - kc0 + 63) >> 6;

    const int lane = tid & 63;
    const int wave = tid >> 6;
    const int wm = (wave & 1) * 64;
    const int wn = (wave >> 1) * 64;
    const int fr = lane & 15;   // row (A) / col (B) within 16-tile
    const int q  = lane >> 4;   // k-quad
    const int f7 = fr & 7;

    // ---- staging source mappings (dest slot fixed: lds = slot*16B) ----
    // A: slot S = i*256+tid -> row r = i*16 + (tid>>4), phys quad pc = tid&15,
    //    logical k-quad c = pc ^ (r&7); (r&7) == ((tid>>4)&7) for all i.
    const int a_c4 = ((tid & 15) ^ ((tid >> 4) & 7)) * 4;   // k offset (floats)
    size_t a_rowoff[8];
#pragma unroll
    for (int i = 0; i < 8; ++i) {
        int r = i * 16 + (tid >> 4);
        if (m0 + r >= N_NODES) r &= 15;      // clamp to valid rows (dupes ok)
        a_rowoff[i] = (size_t)(m0 + r) * N_NODES;
    }
    // B: slot S = i*256+tid -> col = i*32 + (tid>>3), phys quad pq = tid&7,
    //    logical kq = pq ^ (col&7); (col&7) == ((tid>>3)&7) for all i.
    const int b_k8 = ((tid & 7) ^ ((tid >> 3) & 7)) * 8;    // k offset (elems)
    size_t b_coloff[4];
#pragma unroll
    for (int i = 0; i < 4; ++i)
        b_coloff[i] = (size_t)(i * 32 + (tid >> 3)) * XNT_STRIDE;

    f32x4 acc[4][4];
#pragma unroll
    for (int mt = 0; mt < 4; ++mt)
#pragma unroll
        for (int nt = 0; nt < 4; ++nt)
#pragma unroll
            for (int e = 0; e < 4; ++e) acc[mt][nt][e] = 0.f;

    for (int ks = 0; ks < nsub; ++ks) {
        const int k0 = kc0 + ks * 64;

        // ---- async global -> LDS staging (16B per lane per issue) ----
#pragma unroll
        for (int i = 0; i < 8; ++i) {
            int kk = k0 + a_c4;
            if (kk + 4 > kc_end) kk = kc0;   // clamped A x zero B = 0
            GLOAD_LDS16(adj + a_rowoff[i] + kk, Af + (i * 256 + tid) * 4);
        }
#pragma unroll
        for (int i = 0; i < 4; ++i) {
            GLOAD_LDS16(xnt_hi + b_coloff[i] + k0 + b_k8,
                        Bhs + (i * 256 + tid) * 8);
            GLOAD_LDS16(xnt_lo + b_coloff[i] + k0 + b_k8,
                        Bls + (i * 256 + tid) * 8);
        }
        __syncthreads();   // drains vmcnt -> staged data visible

        // ---- two 32-k subtiles of MFMA ----
#pragma unroll
        for (int sub = 0; sub < 2; ++sub) {
            bf16x8 ah[4], al[4], bh[4], bl[4];
#pragma unroll
            for (int mt = 0; mt < 4; ++mt) {
                int r = wm + mt * 16 + fr;
                int c0 = sub * 8 + q * 2;
                int pc0 = c0 ^ f7;
                int pc1 = (c0 + 1) ^ f7;
                float4 fa = *(const float4*)(Af + r * 64 + pc0 * 4);
                float4 fb = *(const float4*)(Af + r * 64 + pc1 * 4);
                split8(fa, fb, ah[mt], al[mt]);
            }
#pragma unroll
            for (int nt = 0; nt < 4; ++nt) {
                int col = wn + nt * 16 + fr;
                int pq = (sub * 4 + q) ^ f7;
                bh[nt] = *(const bf16x8*)(Bhs + col * 64 + pq * 8);
                bl[nt] = *(const bf16x8*)(Bls + col * 64 + pq * 8);
            }
#pragma unroll
            for (int mt = 0; mt < 4; ++mt)
#pragma unroll
                for (int nt = 0; nt < 4; ++nt) {
                    acc[mt][nt] = __builtin_amdgcn_mfma_f32_16x16x32_bf16(ah[mt], bh[nt], acc[mt][nt], 0, 0, 0);
                    acc[mt][nt] = __builtin_amdgcn_mfma_f32_16x16x32_bf16(ah[mt], bl[nt], acc[mt][nt], 0, 0, 0);
                    acc[mt][nt] = __builtin_amdgcn_mfma_f32_16x16x32_bf16(al[mt], bh[nt], acc[mt][nt], 0, 0, 0);
                }
        }
        __syncthreads();   // protect LDS before next iter's staging
    }

    // C/D layout (verified m89): col = lane&15, row = (lane>>4)*4 + reg
    float* P = Ppart + (size_t)blockIdx.y * ((size_t)N_NODES * EMB);
#pragma unroll
    for (int mt = 0; mt < 4; ++mt) {
        int rbase = m0 + wm + mt * 16 + q * 4;
#pragma unroll
        for (int nt = 0; nt < 4; ++nt) {
            int col = wn + nt * 16 + fr;
#pragma unroll
            for (int r = 0; r < 4; ++r) {
                int row = rbase + r;
                if (row < N_NODES)
                    P[(size_t)row * EMB + col] = acc[mt][nt][r];
            }
        }
    }
}

// ---------------------------------------------------------------------------
// epi (fast path): out = tanh(sum_p P[p] + X @ Ws^T)
// ---------------------------------------------------------------------------
__global__ __launch_bounds__(256) void epi_kernel(
    const float* __restrict__ X, const float* __restrict__ Wself,
    const float* __restrict__ Ppart, float* __restrict__ out)
{
    __shared__ float Xl[32 * EMB];
    const int tid = threadIdx.x;
    const int n0 = blockIdx.x * 32;

#pragma unroll
    for (int i = 0; i < 4; ++i) {
        int idx = tid + i * 256;
        int r = idx >> 5;
        int c4 = (idx & 31) << 2;
        int row = n0 + r;
        float4 v = make_float4(0.f, 0.f, 0.f, 0.f);
        if (row < N_NODES) v = *(const float4*)(X + (size_t)row * EMB + c4);
        *(float4*)(Xl + r * EMB + c4) = v;
    }
    __syncthreads();

    const int c = tid & 127;
    const int half = tid >> 7;
    const float* wrow = Wself + c * EMB;

    float acc[16];
#pragma unroll
    for (int r = 0; r < 16; ++r) acc[r] = 0.f;

    for (int k4 = 0; k4 < 32; ++k4) {
        float4 w = *(const float4*)(wrow + k4 * 4);
#pragma unroll
        for (int r = 0; r < 16; ++r) {
            float4 x = *(const float4*)(Xl + (half * 16 + r) * EMB + k4 * 4);
            acc[r] += x.x * w.x + x.y * w.y + x.z * w.z + x.w * w.w;
        }
    }

    if (n0 + half * 16 < N_NODES) {   // whole 16-row group valid (10000%16==0)
        const size_t rb = (size_t)(n0 + half * 16) * EMB + c;
        // reduce the K-chunk partials (coalesced: lanes span c)
#pragma unroll
        for (int p = 0; p < NKCH; ++p) {
            const float* Pp = Ppart + (size_t)p * ((size_t)N_NODES * EMB) + rb;
#pragma unroll
            for (int r = 0; r < 16; ++r)
                acc[r] += Pp[(size_t)r * EMB];
        }
#pragma unroll
        for (int r = 0; r < 16; ++r)
            out[rb + (size_t)r * EMB] = tanhf(acc[r]);
    }
}

// ---------------------------------------------------------------------------
// Fallback path (ws too small): fp32 VALU GEMM Y = adj@X atomically into out,
// then epi0 applies both weight matrices + tanh.
// ---------------------------------------------------------------------------
__global__ __launch_bounds__(256) void gemm0_kernel(
    const float* __restrict__ adj, const float* __restrict__ X,
    float* __restrict__ Y)
{
    __shared__ float As[128 * 33];
    __shared__ float Xs[32 * 132];
    const int tid = threadIdx.x;
    const int m0 = blockIdx.x * 128;
    const int kc0 = blockIdx.y * KC;
    const int kc_end = min(kc0 + KC, N_NODES);
    const int nsub = (kc_end - kc0 + 31) >> 5;

    const int am = tid >> 1, akq = tid & 1;
    const bool arv = (m0 + am) < N_NODES;
    const float* arow_p = adj + (size_t)(m0 + am) * N_NODES;
    const int xr = tid >> 3, xq = tid & 7;
    const int mq = tid >> 4, nq = tid & 15;

    float acc[8][8];
#pragma unroll
    for (int i = 0; i < 8; ++i)
#pragma unroll
        for (int j = 0; j < 8; ++j) acc[i][j] = 0.f;

    for (int ks = 0; ks < nsub; ++ks) {
        int k0 = kc0 + ks * 32;
#pragma unroll
        for (int i = 0; i < 4; ++i) {
            int k = k0 + akq * 16 + i * 4;
            float4 v = make_float4(0.f, 0.f, 0.f, 0.f);
            if (arv && k < kc_end) v = *(const float4*)(arow_p + k);
            float* d = As + am * 33 + akq * 16 + i * 4;
            d[0] = v.x; d[1] = v.y; d[2] = v.z; d[3] = v.w;
        }
#pragma unroll
        for (int i = 0; i < 4; ++i) {
            int c0 = xq * 16 + i * 4;
            int krow = k0 + xr;
            float4 v = make_float4(0.f, 0.f, 0.f, 0.f);
            if (krow < kc_end) v = *(const float4*)(X + (size_t)krow * EMB + c0);
            *(float4*)(Xs + xr * 132 + c0) = v;
        }
        __syncthreads();
        for (int k = 0; k < 32; ++k) {
            float a8[8];
#pragma unroll
            for (int i = 0; i < 8; ++i) a8[i] = As[(mq * 8 + i) * 33 + k];
            float4 x0 = *(const float4*)(Xs + k * 132 + nq * 8);
            float4 x1 = *(const float4*)(Xs + k * 132 + nq * 8 + 4);
            float x8[8] = { x0.x, x0.y, x0.z, x0.w, x1.x, x1.y, x1.z, x1.w };
#pragma unroll
            for (int i = 0; i < 8; ++i)
#pragma unroll
                for (int j = 0; j < 8; ++j) acc[i][j] += a8[i] * x8[j];
        }
        __syncthreads();
    }
#pragma unroll
    for (int i = 0; i < 8; ++i) {
        int row = m0 + mq * 8 + i;
        if (row < N_NODES) {
#pragma unroll
            for (int j = 0; j < 8; ++j)
                atomicAdd(Y + (size_t)row * EMB + nq * 8 + j, acc[i][j]);
        }
    }
}

__global__ __launch_bounds__(256) void epi0_kernel(
    const float* __restrict__ X, const float* __restrict__ Wn,
    const float* __restrict__ Ws, float* __restrict__ out)
{
    __shared__ float Xl[32 * EMB];
    __shared__ float Yl[32 * EMB];
    const int tid = threadIdx.x;
    const int n0 = blockIdx.x * 32;

#pragma unroll
    for (int i = 0; i < 4; ++i) {
        int idx = tid + i * 256;
        int r = idx >> 5;
        int c4 = (idx & 31) << 2;
        int row = n0 + r;
        float4 vx = make_float4(0.f, 0.f, 0.f, 0.f);
        float4 vy = vx;
        if (row < N_NODES) {
            vx = *(const float4*)(X + (size_t)row * EMB + c4);
            vy = *(const float4*)(out + (size_t)row * EMB + c4);
        }
        *(float4*)(Xl + r * EMB + c4) = vx;
        *(float4*)(Yl + r * EMB + c4) = vy;
    }
    __syncthreads();

    const int c = tid & 127;
    const int half = tid >> 7;
    const float* wn = Wn + c * EMB;
    const float* ws = Ws + c * EMB;

    float accn[16], accs[16];
#pragma unroll
    for (int r = 0; r < 16; ++r) { accn[r] = 0.f; accs[r] = 0.f; }

    for (int k4 = 0; k4 < 32; ++k4) {
        float4 a = *(const float4*)(wn + k4 * 4);
        float4 b = *(const float4*)(ws + k4 * 4);
#pragma unroll
        for (int r = 0; r < 16; ++r) {
            float4 y = *(const float4*)(Yl + (half * 16 + r) * EMB + k4 * 4);
            float4 x = *(const float4*)(Xl + (half * 16 + r) * EMB + k4 * 4);
            accn[r] += y.x * a.x + y.y * a.y + y.z * a.z + y.w * a.w;
            accs[r] += x.x * b.x + x.y * b.y + x.z * b.z + x.w * b.w;
        }
    }
#pragma unroll
    for (int r = 0; r < 16; ++r) {
        int row = n0 + half * 16 + r;
        if (row < N_NODES)
            out[(size_t)row * EMB + c] = tanhf(accn[r] + accs[r]);
    }
}

// ---------------------------------------------------------------------------
extern "C" void kernel_launch(void* const* d_in, const int* in_sizes, int n_in,
                              void* d_out, int out_size, void* d_ws, size_t ws_size,
                              hipStream_t stream) {
    const float* adj = (const float*)d_in[0];
    const float* X   = (const float*)d_in[1];
    const float* Wn  = (const float*)d_in[2];
    const float* Ws  = (const float*)d_in[3];
    float* out = (float*)d_out;

    const size_t xnt_elems = (size_t)EMB * XNT_STRIDE;
    const size_t xnt_bytes = xnt_elems * 2 * sizeof(unsigned short);   // hi+lo
    const size_t part_bytes = (size_t)NKCH * N_NODES * EMB * sizeof(float);

    if (ws_size >= xnt_bytes + part_bytes) {
        // fast path: partials in ws, no atomics, no d_out memset
        __bf16* xh = (__bf16*)d_ws;
        __bf16* xl = xh + xnt_elems;
        float* Ppart = (float*)((char*)d_ws + xnt_bytes);
        prep_kernel<<<(N_NODES + 31) / 32, 256, 0, stream>>>(X, Wn, xh, xl);
        gemm_kernel<<<dim3((N_NODES + 127) / 128, NKCH), 256, 0, stream>>>(adj, xh, xl, Ppart);
        epi_kernel<<<(N_NODES + 31) / 32, 256, 0, stream>>>(X, Ws, Ppart, out);
    } else {
        // fallback: fp32 VALU GEMM with atomics into pre-zeroed out
        hipMemsetAsync(d_out, 0, (size_t)N_NODES * EMB * sizeof(float), stream);
        gemm0_kernel<<<dim3((N_NODES + 127) / 128, NKCH), 256, 0, stream>>>(adj, X, out);
        epi0_kernel<<<(N_NODES + 31) / 32, 256, 0, stream>>>(X, Wn, Ws, out);
    }
}